// Round 11
// baseline (31.326 us; speedup 1.0000x reference)
//
#include <hip/hip_runtime.h>

// Problem constants (match reference)
#define BB 8192
#define PP 2048
#define LL 1024
#define OO 1000
#define NPROW 16   // colsum partial row-chunks (128 proto rows each)

typedef float f4v __attribute__((ext_vector_type(4)));

// ws float offsets (no init required: K1 writes everything K2 reads)
#define WS_PCOL 0        // [16][1024] partial colsums
#define WS_WSUM 16384    // [1000] weight row sums
#define WS_SQP  17408    // [64]   per-proto-block sq partials

// ---- K1: proto partials + weight rowsums ----
// grid 1064 x 256.
// Blocks [0,64): proto. bx=blk&3 (256-col chunk), by=blk>>2 (128-row chunk).
//   Coalesced scalar nt loads (read-once). pcol[by][c]; block sq partial via
//   fixed-order LDS tree -> sqp[blk].
// Blocks [64,1064): weight rowsum, 1 row/block. 4 waves each sum a
//   quarter-row (128 float4, nt); butterfly; fixed-order LDS combine.
__global__ void __launch_bounds__(256) k1_pre(
        const float* __restrict__ proto, const float* __restrict__ w,
        float* __restrict__ ws) {
    const int blk = blockIdx.x;
    const int t = threadIdx.x;
    const int wave = t >> 6, lane = t & 63;
    if (blk < 64) {
        const int bx = blk & 3;       // column chunk 0..3
        const int by = blk >> 2;      // row chunk 0..15 (128 rows each)
        const int c = bx * 256 + t;   // column 0..1023
        float csum = 0.f, sq = 0.f;
        const int p0 = by * 128;
#pragma unroll 8
        for (int p = p0; p < p0 + 128; ++p) {
            float v = __builtin_nontemporal_load(&proto[(size_t)p * LL + c]);
            csum += v;
            sq   += v * v;
        }
        ws[WS_PCOL + by * LL + c] = csum;
        __shared__ float red[256];
        red[t] = sq;
        __syncthreads();
        for (int s = 128; s > 0; s >>= 1) {
            if (t < s) red[t] += red[t + s];
            __syncthreads();
        }
        if (t == 0) ws[WS_SQP + blk] = red[0];
    } else {
        const int o = blk - 64;                                  // row 0..999
        const f4v* row = (const f4v*)(w + (size_t)o * PP);       // 512 f4v
        float s = 0.f;
#pragma unroll
        for (int k = 0; k < 2; ++k) {
            f4v v = __builtin_nontemporal_load(row + wave * 128 + k * 64 + lane);
            s += v.x + v.y + v.z + v.w;
        }
        for (int off = 32; off > 0; off >>= 1) s += __shfl_xor(s, off, 64);
        __shared__ float part[4];
        if (lane == 0) part[wave] = s;
        __syncthreads();
        if (t == 0) {
            ws[WS_WSUM + o] = ((part[0] + part[1]) + part[2]) + part[3];
        }
    }
}

// ---- K2: finalize-in-block + 8 samples per block ---- (1024 blocks x 256)
// (a) thread t sums 16 pcol partials for its f4 column group (fixed order,
//     L2-hot normal loads) -> LDS colsum; (b) wave 0 butterfly over sqp[64];
// (c) stage wsum/bias; sync; (d) 2 samples per wave, nt loads on x and nt
//     stores on out (read/write-once streams; keep ws lines resident in L2).
__global__ void __launch_bounds__(256) k2_main(
        const float* __restrict__ x, const float* __restrict__ bias,
        const float* __restrict__ ws, float* __restrict__ out) {
    const int blk = blockIdx.x;
    const int t = threadIdx.x;
    const int wave = t >> 6, lane = t & 63;

    __shared__ f4v s_cs[256];   // colsum, f4 per column group
    __shared__ f4v s_w[256];    // wsum (250 used)
    __shared__ f4v s_b[256];    // bias (250 used)
    __shared__ float s_psq;

    // (a) colsum finalize: 16 f4v loads per thread, fixed order
    {
        const f4v* pc4 = (const f4v*)(ws + WS_PCOL);
        f4v acc = {0.f, 0.f, 0.f, 0.f};
#pragma unroll
        for (int r = 0; r < NPROW; ++r) acc += pc4[r * 256 + t];
        s_cs[t] = acc;
    }
    // (b) psq: wave 0, 64-wide butterfly (fixed order)
    if (wave == 0) {
        float p = ws[WS_SQP + lane];
        for (int off = 32; off > 0; off >>= 1) p += __shfl_xor(p, off, 64);
        if (lane == 0) s_psq = p;
    }
    // (c) stage wsum + bias
    if (t < 250) {
        s_w[t] = ((const f4v*)(ws + WS_WSUM))[t];
        s_b[t] = ((const f4v*)bias)[t];
    }
    __syncthreads();
    const float psq = s_psq;

    // (d) 2 samples per wave, waves independent
#pragma unroll
    for (int s = 0; s < 2; ++s) {
        const int b = blk * 8 + wave * 2 + s;                   // < 8192
        const f4v* xr = (const f4v*)(x + (size_t)b * LL);       // 256 f4v
        float sumsq = 0.f, dotc = 0.f;
#pragma unroll
        for (int k = 0; k < 4; ++k) {
            f4v xv = __builtin_nontemporal_load(xr + lane + 64 * k);
            f4v cv = s_cs[lane + 64 * k];
            sumsq += xv.x * xv.x + xv.y * xv.y + xv.z * xv.z + xv.w * xv.w;
            dotc  += xv.x * cv.x + xv.y * cv.y + xv.z * cv.z + xv.w * cv.w;
        }
        for (int off = 32; off > 0; off >>= 1) {
            sumsq += __shfl_xor(sumsq, off, 64);
            dotc  += __shfl_xor(dotc,  off, 64);
        }
        const float d = sqrtf((float)PP * sumsq - 2.f * dotc + psq);
        f4v* orow = (f4v*)(out + (size_t)b * OO);               // 250 f4v
#pragma unroll
        for (int k = 0; k < 4; ++k) {
            const int idx = lane + 64 * k;
            if (idx < 250) {
                f4v wv = s_w[idx];
                f4v bv = s_b[idx];
                f4v ov;
                ov.x = d * wv.x + bv.x;
                ov.y = d * wv.y + bv.y;
                ov.z = d * wv.z + bv.z;
                ov.w = d * wv.w + bv.w;
                __builtin_nontemporal_store(ov, orow + idx);
            }
        }
    }
}

extern "C" void kernel_launch(void* const* d_in, const int* in_sizes, int n_in,
                              void* d_out, int out_size, void* d_ws, size_t ws_size,
                              hipStream_t stream) {
    const float* input  = (const float*)d_in[0];  // [B, L]
    const float* proto  = (const float*)d_in[1];  // [P, L]
    const float* weight = (const float*)d_in[2];  // [O, P]
    const float* bias   = (const float*)d_in[3];  // [O]
    float* out = (float*)d_out;                   // [B, O]
    float* ws  = (float*)d_ws;

    k1_pre<<<1064, 256, 0, stream>>>(proto, weight, ws);
    k2_main<<<1024, 256, 0, stream>>>(input, bias, ws, out);
}

// Round 12
// 24.528 us; speedup vs baseline: 1.2772x; 1.2772x over previous
//
#include <hip/hip_runtime.h>

// Problem constants (match reference)
#define BB 8192
#define PP 2048
#define LL 1024
#define OO 1000
#define NPROW 32   // colsum partial row-chunks (64 proto rows each)

// ws float offsets (no init required: K1 writes everything K2 reads)
#define WS_PCOL 0        // [32][1024] partial colsums
#define WS_WSUM 32768    // [1000] weight row sums
#define WS_SQP  33792    // [128]  per-proto-block sq partials

// ---- K1: proto partials + weight rowsums (r10 structure, no nt) ----
// grid 1128 x 256.
// Blocks [0,128): proto. bx=blk&3 (256-col chunk), by=blk>>2 (64-row chunk).
//   Coalesced. pcol[by][c]; block sq partial via fixed-order LDS tree.
// Blocks [128,1128): weight rowsum, 1 row/block, 4 waves x quarter-row.
__global__ void __launch_bounds__(256) k1_pre(
        const float* __restrict__ proto, const float* __restrict__ w,
        float* __restrict__ ws) {
    const int blk = blockIdx.x;
    const int t = threadIdx.x;
    const int wave = t >> 6, lane = t & 63;
    if (blk < 128) {
        const int bx = blk & 3;       // column chunk 0..3
        const int by = blk >> 2;      // row chunk 0..31 (64 rows each)
        const int c = bx * 256 + t;   // column 0..1023
        float csum = 0.f, sq = 0.f;
        const int p0 = by * 64;
#pragma unroll 8
        for (int p = p0; p < p0 + 64; ++p) {
            float v = proto[(size_t)p * LL + c];
            csum += v;
            sq   += v * v;
        }
        ws[WS_PCOL + by * LL + c] = csum;
        __shared__ float red[256];
        red[t] = sq;
        __syncthreads();
        for (int s = 128; s > 0; s >>= 1) {
            if (t < s) red[t] += red[t + s];
            __syncthreads();
        }
        if (t == 0) ws[WS_SQP + blk] = red[0];
    } else {
        const int o = blk - 128;                                 // row 0..999
        const float4* row = (const float4*)(w + (size_t)o * PP); // 512 float4
        float s = 0.f;
#pragma unroll
        for (int k = 0; k < 2; ++k) {
            float4 v = row[wave * 128 + k * 64 + lane];
            s += v.x + v.y + v.z + v.w;
        }
        for (int off = 32; off > 0; off >>= 1) s += __shfl_xor(s, off, 64);
        __shared__ float part[4];
        if (lane == 0) part[wave] = s;
        __syncthreads();
        if (t == 0) {
            ws[WS_WSUM + o] = ((part[0] + part[1]) + part[2]) + part[3];
        }
    }
}

// ---- K2: finalize-in-block + 16 samples per block ---- (512 blocks x 256)
// Per block: (a) thread t sums the 32 pcol partials for its float4 column
// group (fixed order, L2-hot) -> LDS colsum; (b) wave 0 reduces sqp[128]
// (2/lane + butterfly, fixed order) -> psq; (c) t<250 stages wsum/bias;
// sync; (d) each wave processes 4 samples independently.
__global__ void __launch_bounds__(256) k2_main(
        const float* __restrict__ x, const float* __restrict__ bias,
        const float* __restrict__ ws, float* __restrict__ out) {
    const int blk = blockIdx.x;
    const int t = threadIdx.x;
    const int wave = t >> 6, lane = t & 63;

    __shared__ float4 s_cs[256];   // colsum, as float4 per column group
    __shared__ float4 s_w[256];    // wsum (250 used)
    __shared__ float4 s_b[256];    // bias (250 used)
    __shared__ float s_psq;

    // (a) colsum finalize: 32 float4 loads per thread, fixed order (L2-hot)
    {
        const float4* pc4 = (const float4*)(ws + WS_PCOL);
        float4 acc = make_float4(0.f, 0.f, 0.f, 0.f);
#pragma unroll
        for (int r = 0; r < NPROW; ++r) {
            float4 v = pc4[r * 256 + t];
            acc.x += v.x; acc.y += v.y; acc.z += v.z; acc.w += v.w;
        }
        s_cs[t] = acc;
    }
    // (b) psq: wave 0, 2 partials per lane (fixed order) then butterfly
    if (wave == 0) {
        float p = ws[WS_SQP + lane] + ws[WS_SQP + 64 + lane];
        for (int off = 32; off > 0; off >>= 1) p += __shfl_xor(p, off, 64);
        if (lane == 0) s_psq = p;
    }
    // (c) stage wsum + bias
    if (t < 250) {
        s_w[t] = ((const float4*)(ws + WS_WSUM))[t];
        s_b[t] = ((const float4*)bias)[t];
    }
    __syncthreads();
    const float psq = s_psq;

    // (d) 4 samples per wave, waves independent
#pragma unroll
    for (int s = 0; s < 4; ++s) {
        const int b = blk * 16 + wave * 4 + s;                  // < 8192
        const float4* xr = (const float4*)(x + (size_t)b * LL); // 256 float4
        float sumsq = 0.f, dotc = 0.f;
#pragma unroll
        for (int k = 0; k < 4; ++k) {
            float4 xv = xr[lane + 64 * k];
            float4 cv = s_cs[lane + 64 * k];
            sumsq += xv.x * xv.x + xv.y * xv.y + xv.z * xv.z + xv.w * xv.w;
            dotc  += xv.x * cv.x + xv.y * cv.y + xv.z * cv.z + xv.w * cv.w;
        }
        for (int off = 32; off > 0; off >>= 1) {
            sumsq += __shfl_xor(sumsq, off, 64);
            dotc  += __shfl_xor(dotc,  off, 64);
        }
        const float d = sqrtf((float)PP * sumsq - 2.f * dotc + psq);
        float4* orow = (float4*)(out + (size_t)b * OO);         // 250 float4
#pragma unroll
        for (int k = 0; k < 4; ++k) {
            const int idx = lane + 64 * k;
            if (idx < 250) {
                float4 wv = s_w[idx];
                float4 bv = s_b[idx];
                float4 ov;
                ov.x = d * wv.x + bv.x;
                ov.y = d * wv.y + bv.y;
                ov.z = d * wv.z + bv.z;
                ov.w = d * wv.w + bv.w;
                orow[idx] = ov;
            }
        }
    }
}

extern "C" void kernel_launch(void* const* d_in, const int* in_sizes, int n_in,
                              void* d_out, int out_size, void* d_ws, size_t ws_size,
                              hipStream_t stream) {
    const float* input  = (const float*)d_in[0];  // [B, L]
    const float* proto  = (const float*)d_in[1];  // [P, L]
    const float* weight = (const float*)d_in[2];  // [O, P]
    const float* bias   = (const float*)d_in[3];  // [O]
    float* out = (float*)d_out;                   // [B, O]
    float* ws  = (float*)d_ws;

    k1_pre<<<1128, 256, 0, stream>>>(proto, weight, ws);
    k2_main<<<512, 256, 0, stream>>>(input, bias, ws, out);
}